// Round 16
// baseline (282.266 us; speedup 1.0000x reference)
//
#include <hip/hip_runtime.h>
#include <hip/hip_bf16.h>
#include <math.h>

typedef __bf16 bf16_t;
typedef bf16_t bf16x8 __attribute__((ext_vector_type(8)));
typedef bf16_t bf16x4 __attribute__((ext_vector_type(4)));
typedef float  f32x4  __attribute__((ext_vector_type(4)));

#define MFMA_16x16x32_BF16(a, b, c) __builtin_amdgcn_mfma_f32_16x16x32_bf16((a), (b), (c), 0, 0, 0)

static constexpr int BB = 4, TT = 2048, CC = 1024, HH = 16, HD = 64;
static constexpr int C3 = 3 * CC;   // 3072
static constexpr int MM = BB * TT;  // 8192 rows
static constexpr size_t SL = (size_t)BB * HH * TT * HD;  // elems per q/k/v slice

__device__ __forceinline__ float fast_exp2(float x) {
  float r;
  asm("v_exp_f32 %0, %1" : "=v"(r) : "v"(x));
  return r;
}

// async global->LDS, 16B per lane; LDS dest must be wave-uniform base (+lane*16 implicit)
__device__ __forceinline__ void gload16(const void* g, void* l) {
  __builtin_amdgcn_global_load_lds(
      (const __attribute__((address_space(1))) unsigned int*)g,
      (__attribute__((address_space(3))) unsigned int*)l, 16, 0, 0);
}

// ---------------- cast x (fp32) -> xb (bf16) ----------------
__global__ void cast_x_kernel(const float* __restrict__ x, bf16_t* __restrict__ xb, int n4) {
  int i = blockIdx.x * blockDim.x + threadIdx.x;
  if (i >= n4) return;
  float4 v = reinterpret_cast<const float4*>(x)[i];
  bf16x4 o;
  o[0] = (bf16_t)v.x; o[1] = (bf16_t)v.y; o[2] = (bf16_t)v.z; o[3] = (bf16_t)v.w;
  reinterpret_cast<bf16x4*>(xb)[i] = o;
}

// ------------- transpose+cast weights: in fp32 [R][Cn] -> out bf16 [Cn][R] -------------
__global__ void transpose_cast_kernel(const float* __restrict__ in, bf16_t* __restrict__ out,
                                      int R, int Cn) {
  __shared__ float tile[32][33];
  int c0 = blockIdx.x * 32, r0 = blockIdx.y * 32;
  int tx = threadIdx.x, ty = threadIdx.y;
#pragma unroll
  for (int i = 0; i < 4; ++i)
    tile[ty + 8 * i][tx] = in[(size_t)(r0 + ty + 8 * i) * Cn + c0 + tx];
  __syncthreads();
#pragma unroll
  for (int i = 0; i < 4; ++i)
    out[(size_t)(c0 + ty + 8 * i) * R + r0 + tx] = (bf16_t)tile[tx][ty + 8 * i];
}

// ------------- concat biases [bq | bkv] -> bias_cat[3072] -------------
__global__ void concat_bias_kernel(const float* __restrict__ bq, const float* __restrict__ bkv,
                                   float* __restrict__ dst) {
  int i = blockIdx.x * 256 + threadIdx.x;
  if (i >= 3072) return;
  const float* p = (i < 1024) ? (bq + i) : (bkv + i - 1024);
  dst[i] = *p;
}

// ---------------- GEMM: C[M,N] = A[M,K] * Bt[N,K]^T + bias (r15, unchanged) ----------------
__device__ inline void store_out(float* p, float v)  { *p = v; }
__device__ inline void store_out(bf16_t* p, float v) { *p = (bf16_t)v; }

template <int SPLIT, typename OutT>
__global__ __launch_bounds__(512, 2) void gemm_kernel(
    const bf16_t* __restrict__ A, const bf16_t* __restrict__ Bt, OutT* __restrict__ C,
    bf16_t* __restrict__ Vt, const float* __restrict__ bias, int M, int N, int K, int gx) {
  __shared__ bf16_t As[256][64];   // 32 KB
  __shared__ bf16_t Bs[128][64];   // 16 KB
  const int tid = threadIdx.x;
  const int wid = tid >> 6, lane = tid & 63;
  const int lhi = lane >> 4, llo = lane & 15;
  const int wm = (wid >> 1) * 64, wn = (wid & 1) * 64;   // 4x2 wave grid -> 256x128
  const int bid = blockIdx.x;
  const int xcd = bid & 7, lb = bid >> 3;
  const int bandw = gx >> 3;                      // gx % 8 == 0
  const int bx = xcd * bandw + (lb % bandw);      // A band per XCD (L2-resident)
  const int by = lb / bandw;                      // bx-major within XCD
  const int m0 = bx * 256, n0 = by * 128;
  const int l8 = lane >> 3;                       // row within 8-row group
  const int s8 = ((lane & 7) ^ l8) * 8;           // swizzled source slot (elems)

  const bf16_t* gA = A + (size_t)(m0 + wid * 32 + l8) * K + s8;
  const bf16_t* gB = Bt + (size_t)(n0 + wid * 16 + l8) * K + s8;
  bf16_t* lA = &As[wid * 32][0];   // wave-uniform
  bf16_t* lB = &Bs[wid * 16][0];
  const int rs0 = (lhi ^ (llo & 7)) * 16;         // read slot (bytes); kk=1 -> ^64

  f32x4 acc[4][4] = {};
  for (int k0 = 0; k0 < K; k0 += 64) {
    __syncthreads();
#pragma unroll
    for (int g = 0; g < 4; ++g)
      gload16(gA + k0 + (size_t)(8 * g) * K, lA + 8 * g * 64);
#pragma unroll
    for (int g = 0; g < 2; ++g)
      gload16(gB + k0 + (size_t)(8 * g) * K, lB + 8 * g * 64);
    __syncthreads();
#pragma unroll
    for (int kk = 0; kk < 2; ++kk) {
      const int ro = rs0 ^ (kk * 64);
      bf16x8 af[4], bfr[4];
#pragma unroll
      for (int mi = 0; mi < 4; ++mi)
        af[mi] = *(const bf16x8*)((const char*)&As[wm + mi * 16 + llo][0] + ro);
#pragma unroll
      for (int ni = 0; ni < 4; ++ni)
        bfr[ni] = *(const bf16x8*)((const char*)&Bs[wn + ni * 16 + llo][0] + ro);
#pragma unroll
      for (int mi = 0; mi < 4; ++mi)
#pragma unroll
        for (int ni = 0; ni < 4; ++ni)
          acc[mi][ni] = MFMA_16x16x32_BF16(af[mi], bfr[ni], acc[mi][ni]);
    }
  }

#pragma unroll
  for (int mi = 0; mi < 4; ++mi) {
#pragma unroll
    for (int ni = 0; ni < 4; ++ni) {
      const int row0 = m0 + wm + mi * 16 + 4 * lhi;
      const int col  = n0 + wn + ni * 16 + llo;
      const float bv = bias[col];
      if constexpr (SPLIT) {
        const int sel = col >> 10, rem = col & 1023;
        const int hh = rem >> 6, dd = rem & 63;
        const int bb = row0 >> 11, t0 = row0 & 2047;   // rows row0..row0+3 share bb, t0>>5
        if (sel == 2) {
          // V -> tiled-transposed vt[bh][t/32][64][32], 4 consecutive t = bf16x4
          size_t addr = (((size_t)bb * HH + hh) * TT) * HD +
                        (size_t)(t0 >> 5) * 2048 + (size_t)dd * 32 + (t0 & 31);
          bf16x4 o;
#pragma unroll
          for (int r = 0; r < 4; ++r) o[r] = (bf16_t)(acc[mi][ni][r] + bv);
          *(bf16x4*)&Vt[addr] = o;
        } else {
          size_t base = ((((size_t)sel * BB + bb) * HH + hh) * TT + t0) * HD + dd;
#pragma unroll
          for (int r = 0; r < 4; ++r)
            ((bf16_t*)C)[base + (size_t)r * HD] = (bf16_t)(acc[mi][ni][r] + bv);
        }
      } else {
#pragma unroll
        for (int r = 0; r < 4; ++r)
          store_out(&C[(size_t)(row0 + r) * N + col], acc[mi][ni][r] + bv);
      }
    }
  }
}

// ---------------- flash attention, ALiBi, causal — fully LDS-staged (r16) ----------------
// r13 structure + r16 delta: the per-wave strided direct-load diagonal tails are FOLDED
// into the staged loop. Staged range extends to [ksm, kvT+128): +2 block-uniform
// iterations (barrier-legal). Waves past their causal end skip compute behind a
// wave-uniform guard but still hit the barrier; the last two iterations apply the
// per-element causal mask + dead-chunk skip reading K/V from LDS. Zero strided loads.
__global__ __launch_bounds__(256, 3) void attn_kernel(
    const bf16_t* __restrict__ qh,   // [BH][T][64]
    const bf16_t* __restrict__ kh,   // [BH][T][64]
    const bf16_t* __restrict__ vt,   // [BH][T/32][64][32] tiled V^T
    const float* __restrict__ alibi_m,
    bf16_t* __restrict__ y) {        // [B*T][CC]
  __shared__ bf16_t Klds[2][64][64];        // 16 KB, slot-swizzled rows
  __shared__ bf16_t Vlds[2][2][64][32];     // 16 KB, slot-swizzled rows
  __shared__ bf16_t Plds[4][32][68];        // 17.4 KB, per-wave
  const int tid = threadIdx.x, wid = tid >> 6, lane = tid & 63;
  const int lhi = lane >> 4, llo = lane & 15;
  const int bid = blockIdx.x;
  const int x = bid & 7, u = bid >> 3;
  const int b = u & 3, sel = (u >> 2) & 1, jtd = u >> 3;
  const int h = sel ? (15 - x) : x;
  const int jt = 15 - jtd;                  // LPT: longest tiles dispatched first
  const int bh = b * HH + h;
  const int q0 = jt * 128 + wid * 32;

  const float mh2 = alibi_m[h] * 1.44269504f;   // ALiBi slope in exp2 units
  const float C1 = 0.18033688f;                 // 0.125 * log2(e)
  const float M0 = 17.3f;                       // static max; p bounded, no overflow
  const int Dwin = (int)(40.0f / mh2);          // dropped keys: rel weight < ~2^-40

  const bf16_t* qbase = qh + (size_t)bh * TT * HD;
  const bf16_t* kbase = kh + (size_t)bh * TT * HD;
  const bf16_t* vbase = vt + (size_t)bh * TT * HD;

  // head-level constants
  float frm[2][4], w16c[4];
#pragma unroll
  for (int f = 0; f < 2; ++f)
#pragma unroll
    for (int r = 0; r < 4; ++r) frm[f][r] = (float)(16 * f + r) * mh2;
#pragma unroll
  for (int c = 0; c < 4; ++c) w16c[c] = fast_exp2((float)(16 * c) * mh2);

  // staging source offsets (per-lane), linear wave-uniform dests
  const int l8 = lane >> 3;
  const size_t kst = (size_t)(wid * 8 + l8) * 64 + ((lane & 7) ^ l8) * 8;
  const int vf_st = ((lane >> 2) & 3) ^ ((lane >> 4) & 3);
  const size_t vst = (size_t)(wid * 16 + (lane >> 2)) * 32 + ((lane & 3) ^ vf_st) * 8;

#define STAGE(BUF, KV0)                                                          \
  do {                                                                           \
    const bf16_t* ks_ = kbase + (size_t)(KV0) * HD + kst;                        \
    bf16_t* kd_ = &Klds[BUF][0][0] + wid * 512;                                  \
    gload16(ks_, kd_);                                                           \
    gload16(ks_ + 2048, kd_ + 2048);                                             \
    const bf16_t* vs_ = vbase + ((size_t)((KV0) >> 5)) * 2048 + vst;             \
    bf16_t* vd_ = &Vlds[BUF][0][0][0] + wid * 512;                               \
    gload16(vs_, vd_);                                                           \
    gload16(vs_ + 2048, vd_ + 2048);                                             \
  } while (0)

  bf16x8 qf[2][2];
#pragma unroll
  for (int f = 0; f < 2; ++f) {
    const bf16_t* qp = qbase + (size_t)(q0 + 16 * f + llo) * HD + 8 * lhi;
    qf[f][0] = *(const bf16x8*)qp;
    qf[f][1] = *(const bf16x8*)(qp + 32);
  }

  f32x4 acc[2][4] = {};
  float lsum[2][4] = {};
  const float bias0 = mh2 * (float)(llo - 4 * lhi - q0) - M0;

  const int kvT = jt * 128;                      // diagonal region base (block-uniform)
  int ksm = kvT - Dwin; ksm = (ksm < 0) ? 0 : (ksm & ~63);
  const int nIter = (kvT - ksm) >> 6;            // unmasked staged iterations
  const int nTot = nIter + 2;                    // + 2 masked diagonal iterations

  STAGE(0, ksm);
  __syncthreads();

  const int krd0 = (lhi ^ (llo & 7)) * 16;       // K read slot bytes (h=0)
  const int krd1 = ((4 + lhi) ^ (llo & 7)) * 16; // h=1
  const int vrd = (lhi ^ ((llo & 3) ^ ((llo >> 2) & 3))) * 16;

  int buf = 0;
#pragma unroll 1
  for (int it = 0; it < nTot; ++it) {
    const int kv0 = ksm + (it << 6);
    if (it + 1 < nTot) STAGE(buf ^ 1, kv0 + 64);   // max staged row kvT+127 <= 2047
    const char* kb = (const char*)&Klds[buf][0][0];
    const char* vb = (const char*)&Vlds[buf][0][0][0];
    if (kv0 <= q0 + 31) {                          // wave-uniform: this wave has live rows
      if (it < nIter) {
        // ---- unmasked iteration ----
        f32x4 s[2][4];
#pragma unroll
        for (int c = 0; c < 4; ++c) {
          bf16x8 k0 = *(const bf16x8*)(kb + (16 * c + llo) * 128 + krd0);
          bf16x8 k1 = *(const bf16x8*)(kb + (16 * c + llo) * 128 + krd1);
          s[0][c] = MFMA_16x16x32_BF16(qf[0][0], k0, f32x4{});
          s[0][c] = MFMA_16x16x32_BF16(qf[0][1], k1, s[0][c]);
          s[1][c] = MFMA_16x16x32_BF16(qf[1][0], k0, f32x4{});
          s[1][c] = MFMA_16x16x32_BF16(qf[1][1], k1, s[1][c]);
        }
        bf16x8 vv[4][2];
#pragma unroll
        for (int d = 0; d < 4; ++d) {
          vv[d][0] = *(const bf16x8*)(vb + (16 * d + llo) * 64 + vrd);
          vv[d][1] = *(const bf16x8*)(vb + 4096 + (16 * d + llo) * 64 + vrd);
        }
        const float tb0 = fmaf(mh2, (float)kv0, bias0);
#pragma unroll
        for (int f = 0; f < 2; ++f) {
#pragma unroll
          for (int r = 0; r < 4; ++r) {
            const float rb = tb0 - frm[f][r];
#pragma unroll
            for (int c = 0; c < 4; ++c) {
              float pv = fast_exp2(fmaf(s[f][c][r], C1, rb)) * w16c[c];
              lsum[f][r] += pv;
              Plds[wid][16 * f + 4 * lhi + r][16 * c + llo] = (bf16_t)pv;
            }
          }
        }
#pragma unroll
        for (int f = 0; f < 2; ++f) {
          const bf16x8 pa0 = *(const bf16x8*)&Plds[wid][16 * f + llo][8 * lhi];
          const bf16x8 pa1 = *(const bf16x8*)&Plds[wid][16 * f + llo][32 + 8 * lhi];
#pragma unroll
          for (int d = 0; d < 4; ++d) {
            acc[f][d] = MFMA_16x16x32_BF16(pa0, vv[d][0], acc[f][d]);
            acc[f][d] = MFMA_16x16x32_BF16(pa1, vv[d][1], acc[f][d]);
          }
        }
      } else {
        // ---- masked diagonal iteration (from LDS) ----
        const int d31 = q0 + 31 - kv0;              // max live 16c (wave-uniform, >=0 here)
        const int dbase = q0 + 4 * lhi - llo - kv0; // keep iff 16c-16f-r <= dbase
        f32x4 s[2][4];
#pragma unroll
        for (int c = 0; c < 4; ++c) {
          if (16 * c > d31) continue;               // wave-uniform dead-chunk skip
          bf16x8 k0 = *(const bf16x8*)(kb + (16 * c + llo) * 128 + krd0);
          bf16x8 k1 = *(const bf16x8*)(kb + (16 * c + llo) * 128 + krd1);
          s[0][c] = MFMA_16x16x32_BF16(qf[0][0], k0, f32x4{});
          s[0][c] = MFMA_16x16x32_BF16(qf[0][1], k1, s[0][c]);
          s[1][c] = MFMA_16x16x32_BF16(qf[1][0], k0, f32x4{});
          s[1][c] = MFMA_16x16x32_BF16(qf[1][1], k1, s[1][c]);
        }
        bf16x8 vv[4][2];
#pragma unroll
        for (int d = 0; d < 4; ++d) {
          vv[d][0] = *(const bf16x8*)(vb + (16 * d + llo) * 64 + vrd);
          vv[d][1] = *(const bf16x8*)(vb + 4096 + (16 * d + llo) * 64 + vrd);
        }
        const float tb0 = fmaf(mh2, (float)kv0, bias0);
#pragma unroll
        for (int f = 0; f < 2; ++f) {
#pragma unroll
          for (int r = 0; r < 4; ++r) {
            const float rb = tb0 - frm[f][r];
#pragma unroll
            for (int c = 0; c < 4; ++c) {
              float pv = 0.f;
              if (16 * c <= d31) {
                pv = fast_exp2(fmaf(s[f][c][r], C1, rb)) * w16c[c];
                pv = (16 * c - 16 * f - r <= dbase) ? pv : 0.f;
                lsum[f][r] += pv;
              }
              Plds[wid][16 * f + 4 * lhi + r][16 * c + llo] = (bf16_t)pv;
            }
          }
        }
#pragma unroll
        for (int f = 0; f < 2; ++f) {
          const bf16x8 pa0 = *(const bf16x8*)&Plds[wid][16 * f + llo][8 * lhi];
          const bf16x8 pa1 = *(const bf16x8*)&Plds[wid][16 * f + llo][32 + 8 * lhi];
#pragma unroll
          for (int d = 0; d < 4; ++d) {
            acc[f][d] = MFMA_16x16x32_BF16(pa0, vv[d][0], acc[f][d]);
            acc[f][d] = MFMA_16x16x32_BF16(pa1, vv[d][1], acc[f][d]);
          }
        }
      }
    }
    __syncthreads();   // reads of buf done + staging of buf^1 landed (all 256 threads)
    buf ^= 1;
  }
#undef STAGE

  // ---- one l-reduction across the 16-lane row group; epilogue ----
#pragma unroll
  for (int f = 0; f < 2; ++f) {
    float rl[4];
#pragma unroll
    for (int r = 0; r < 4; ++r) {
#pragma unroll
      for (int off = 1; off < 16; off <<= 1)
        lsum[f][r] += __shfl_xor(lsum[f][r], off, 64);
      rl[r] = __builtin_amdgcn_rcpf(lsum[f][r]);
    }
#pragma unroll
    for (int d = 0; d < 4; ++d)
#pragma unroll
      for (int r = 0; r < 4; ++r) {
        const int row = q0 + 16 * f + 4 * lhi + r;
        y[(size_t)(b * TT + row) * CC + h * HD + 16 * d + llo] =
            (bf16_t)(acc[f][d][r] * rl[r]);
      }
  }
}

// ---------------- launch ----------------
extern "C" void kernel_launch(void* const* d_in, const int* in_sizes, int n_in,
                              void* d_out, int out_size, void* d_ws, size_t ws_size,
                              hipStream_t stream) {
  const float* x       = (const float*)d_in[0];
  const float* Wq      = (const float*)d_in[1];
  const float* bq      = (const float*)d_in[2];
  const float* Wkv     = (const float*)d_in[3];
  const float* bkv     = (const float*)d_in[4];
  const float* Wp      = (const float*)d_in[5];
  const float* bp      = (const float*)d_in[6];
  const float* alibi_m = (const float*)d_in[7];
  float* out = (float*)d_out;

  char* w = (char*)d_ws;
  bf16_t* xb   = (bf16_t*)w; w += (size_t)MM * CC * 2;        // 16.78 MB (reused as yb)
  bf16_t* qkvh = (bf16_t*)w; w += SL * 3 * 2;                 // qkvh: q,k slices used
  bf16_t* btq  = (bf16_t*)w; w += (size_t)C3 * CC * 2;        //  6.29 MB
  bf16_t* wpt  = (bf16_t*)w; w += (size_t)CC * CC * 2;        //  2.10 MB
  bf16_t* vtb  = (bf16_t*)w; w += SL * 2;                     // 16.78 MB  [BH][T/32][64][32]
  float*  bcat = (float*)w;  w += (size_t)C3 * 4;             // 12 KB
  bf16_t* yb   = xb;  // xb dead after QKV GEMM -> alias

  dim3 tb(32, 8);
  cast_x_kernel<<<8192, 256, 0, stream>>>(x, xb, MM * CC / 4);
  transpose_cast_kernel<<<dim3(32, 32), tb, 0, stream>>>(Wq, btq, 1024, 1024);
  transpose_cast_kernel<<<dim3(64, 32), tb, 0, stream>>>(Wkv, btq + (size_t)1024 * 1024, 1024, 2048);
  transpose_cast_kernel<<<dim3(32, 32), tb, 0, stream>>>(Wp, wpt, 1024, 1024);
  concat_bias_kernel<<<12, 256, 0, stream>>>(bq, bkv, bcat);

  // QKV: 256x128 tiles, grid 768 (96/XCD, A band 2MB L2-resident);
  // V columns written directly into vtb (tiled V^T).
  gemm_kernel<1, bf16_t><<<dim3(768), 512, 0, stream>>>(
      xb, btq, qkvh, vtb, bcat, MM, C3, CC, 32);
  attn_kernel<<<dim3(1024), 256, 0, stream>>>(qkvh, qkvh + SL, vtb, alibi_m, yb);
  // proj: 256x128 tiles, grid 256
  gemm_kernel<0, float><<<dim3(256), 512, 0, stream>>>(
      yb, wpt, out, nullptr, bp, MM, CC, CC, 32);
}

// Round 17
// 165.758 us; speedup vs baseline: 1.7029x; 1.7029x over previous
//
#include <hip/hip_runtime.h>
#include <hip/hip_bf16.h>
#include <math.h>

typedef __bf16 bf16_t;
typedef bf16_t bf16x8 __attribute__((ext_vector_type(8)));
typedef bf16_t bf16x4 __attribute__((ext_vector_type(4)));
typedef float  f32x4  __attribute__((ext_vector_type(4)));

#define MFMA_16x16x32_BF16(a, b, c) __builtin_amdgcn_mfma_f32_16x16x32_bf16((a), (b), (c), 0, 0, 0)

static constexpr int BB = 4, TT = 2048, CC = 1024, HH = 16, HD = 64;
static constexpr int C3 = 3 * CC;   // 3072
static constexpr int MM = BB * TT;  // 8192 rows
static constexpr size_t SL = (size_t)BB * HH * TT * HD;  // elems per q/k/v slice

__device__ __forceinline__ float fast_exp2(float x) {
  float r;
  asm("v_exp_f32 %0, %1" : "=v"(r) : "v"(x));
  return r;
}

// async global->LDS, 16B per lane; LDS dest must be wave-uniform base (+lane*16 implicit)
__device__ __forceinline__ void gload16(const void* g, void* l) {
  __builtin_amdgcn_global_load_lds(
      (const __attribute__((address_space(1))) unsigned int*)g,
      (__attribute__((address_space(3))) unsigned int*)l, 16, 0, 0);
}

// ---------------- cast x (fp32) -> xb (bf16) ----------------
__global__ void cast_x_kernel(const float* __restrict__ x, bf16_t* __restrict__ xb, int n4) {
  int i = blockIdx.x * blockDim.x + threadIdx.x;
  if (i >= n4) return;
  float4 v = reinterpret_cast<const float4*>(x)[i];
  bf16x4 o;
  o[0] = (bf16_t)v.x; o[1] = (bf16_t)v.y; o[2] = (bf16_t)v.z; o[3] = (bf16_t)v.w;
  reinterpret_cast<bf16x4*>(xb)[i] = o;
}

// ------------- transpose+cast weights: in fp32 [R][Cn] -> out bf16 [Cn][R] -------------
__global__ void transpose_cast_kernel(const float* __restrict__ in, bf16_t* __restrict__ out,
                                      int R, int Cn) {
  __shared__ float tile[32][33];
  int c0 = blockIdx.x * 32, r0 = blockIdx.y * 32;
  int tx = threadIdx.x, ty = threadIdx.y;
#pragma unroll
  for (int i = 0; i < 4; ++i)
    tile[ty + 8 * i][tx] = in[(size_t)(r0 + ty + 8 * i) * Cn + c0 + tx];
  __syncthreads();
#pragma unroll
  for (int i = 0; i < 4; ++i)
    out[(size_t)(c0 + ty + 8 * i) * R + r0 + tx] = (bf16_t)tile[tx][ty + 8 * i];
}

// ------------- concat biases [bq | bkv] -> bias_cat[3072] -------------
__global__ void concat_bias_kernel(const float* __restrict__ bq, const float* __restrict__ bkv,
                                   float* __restrict__ dst) {
  int i = blockIdx.x * 256 + threadIdx.x;
  if (i >= 3072) return;
  const float* p = (i < 1024) ? (bq + i) : (bkv + i - 1024);
  dst[i] = *p;
}

// ---------------- GEMM: C[M,N] = A[M,K] * Bt[N,K]^T + bias (r15, unchanged) ----------------
__device__ inline void store_out(float* p, float v)  { *p = v; }
__device__ inline void store_out(bf16_t* p, float v) { *p = (bf16_t)v; }

template <int SPLIT, typename OutT>
__global__ __launch_bounds__(512, 2) void gemm_kernel(
    const bf16_t* __restrict__ A, const bf16_t* __restrict__ Bt, OutT* __restrict__ C,
    bf16_t* __restrict__ Vt, const float* __restrict__ bias, int M, int N, int K, int gx) {
  __shared__ bf16_t As[256][64];   // 32 KB
  __shared__ bf16_t Bs[128][64];   // 16 KB
  const int tid = threadIdx.x;
  const int wid = tid >> 6, lane = tid & 63;
  const int lhi = lane >> 4, llo = lane & 15;
  const int wm = (wid >> 1) * 64, wn = (wid & 1) * 64;   // 4x2 wave grid -> 256x128
  const int bid = blockIdx.x;
  const int xcd = bid & 7, lb = bid >> 3;
  const int bandw = gx >> 3;                      // gx % 8 == 0
  const int bx = xcd * bandw + (lb % bandw);      // A band per XCD (L2-resident)
  const int by = lb / bandw;                      // bx-major within XCD
  const int m0 = bx * 256, n0 = by * 128;
  const int l8 = lane >> 3;                       // row within 8-row group
  const int s8 = ((lane & 7) ^ l8) * 8;           // swizzled source slot (elems)

  const bf16_t* gA = A + (size_t)(m0 + wid * 32 + l8) * K + s8;
  const bf16_t* gB = Bt + (size_t)(n0 + wid * 16 + l8) * K + s8;
  bf16_t* lA = &As[wid * 32][0];   // wave-uniform
  bf16_t* lB = &Bs[wid * 16][0];
  const int rs0 = (lhi ^ (llo & 7)) * 16;         // read slot (bytes); kk=1 -> ^64

  f32x4 acc[4][4] = {};
  for (int k0 = 0; k0 < K; k0 += 64) {
    __syncthreads();
#pragma unroll
    for (int g = 0; g < 4; ++g)
      gload16(gA + k0 + (size_t)(8 * g) * K, lA + 8 * g * 64);
#pragma unroll
    for (int g = 0; g < 2; ++g)
      gload16(gB + k0 + (size_t)(8 * g) * K, lB + 8 * g * 64);
    __syncthreads();
#pragma unroll
    for (int kk = 0; kk < 2; ++kk) {
      const int ro = rs0 ^ (kk * 64);
      bf16x8 af[4], bfr[4];
#pragma unroll
      for (int mi = 0; mi < 4; ++mi)
        af[mi] = *(const bf16x8*)((const char*)&As[wm + mi * 16 + llo][0] + ro);
#pragma unroll
      for (int ni = 0; ni < 4; ++ni)
        bfr[ni] = *(const bf16x8*)((const char*)&Bs[wn + ni * 16 + llo][0] + ro);
#pragma unroll
      for (int mi = 0; mi < 4; ++mi)
#pragma unroll
        for (int ni = 0; ni < 4; ++ni)
          acc[mi][ni] = MFMA_16x16x32_BF16(af[mi], bfr[ni], acc[mi][ni]);
    }
  }

#pragma unroll
  for (int mi = 0; mi < 4; ++mi) {
#pragma unroll
    for (int ni = 0; ni < 4; ++ni) {
      const int row0 = m0 + wm + mi * 16 + 4 * lhi;
      const int col  = n0 + wn + ni * 16 + llo;
      const float bv = bias[col];
      if constexpr (SPLIT) {
        const int sel = col >> 10, rem = col & 1023;
        const int hh = rem >> 6, dd = rem & 63;
        const int bb = row0 >> 11, t0 = row0 & 2047;   // rows row0..row0+3 share bb, t0>>5
        if (sel == 2) {
          // V -> tiled-transposed vt[bh][t/32][64][32], 4 consecutive t = bf16x4
          size_t addr = (((size_t)bb * HH + hh) * TT) * HD +
                        (size_t)(t0 >> 5) * 2048 + (size_t)dd * 32 + (t0 & 31);
          bf16x4 o;
#pragma unroll
          for (int r = 0; r < 4; ++r) o[r] = (bf16_t)(acc[mi][ni][r] + bv);
          *(bf16x4*)&Vt[addr] = o;
        } else {
          size_t base = ((((size_t)sel * BB + bb) * HH + hh) * TT + t0) * HD + dd;
#pragma unroll
          for (int r = 0; r < 4; ++r)
            ((bf16_t*)C)[base + (size_t)r * HD] = (bf16_t)(acc[mi][ni][r] + bv);
        }
      } else {
#pragma unroll
        for (int r = 0; r < 4; ++r)
          store_out(&C[(size_t)(row0 + r) * N + col], acc[mi][ni][r] + bv);
      }
    }
  }
}

// ---------------- flash attention, ALiBi, causal — fully LDS-staged, UNIFORM body ----------------
// r15 structure; r17 delta: staged loop extended by 2 iterations to cover the diagonal
// region [kvT, kvT+128), strided per-wave tails DELETED, causal mask folded into the
// single uniform body as per-element cndmask (r7-proven ~free). No branches around
// arrays, static indices only -> no rule-#20 local-mem demotion (r16's failure mode).
// Early waves waste <=1 fully-masked iteration (uniform control flow, barrier-legal).
__global__ __launch_bounds__(256, 3) void attn_kernel(
    const bf16_t* __restrict__ qh,   // [BH][T][64]
    const bf16_t* __restrict__ kh,   // [BH][T][64]
    const bf16_t* __restrict__ vt,   // [BH][T/32][64][32] tiled V^T
    const float* __restrict__ alibi_m,
    bf16_t* __restrict__ y) {        // [B*T][CC]
  __shared__ bf16_t Klds[2][64][64];        // 16 KB, slot-swizzled rows
  __shared__ bf16_t Vlds[2][2][64][32];     // 16 KB, slot-swizzled rows
  __shared__ bf16_t Plds[4][32][68];        // 17.4 KB, per-wave
  const int tid = threadIdx.x, wid = tid >> 6, lane = tid & 63;
  const int lhi = lane >> 4, llo = lane & 15;
  const int bid = blockIdx.x;
  const int x = bid & 7, u = bid >> 3;
  const int b = u & 3, sel = (u >> 2) & 1, jtd = u >> 3;
  const int h = sel ? (15 - x) : x;
  const int jt = 15 - jtd;                  // LPT: longest tiles dispatched first
  const int bh = b * HH + h;
  const int q0 = jt * 128 + wid * 32;

  const float mh2 = alibi_m[h] * 1.44269504f;   // ALiBi slope in exp2 units
  const float C1 = 0.18033688f;                 // 0.125 * log2(e)
  const float M0 = 17.3f;                       // static max; p bounded, no overflow
  const int Dwin = (int)(40.0f / mh2);          // dropped keys: rel weight < ~2^-40

  const bf16_t* qbase = qh + (size_t)bh * TT * HD;
  const bf16_t* kbase = kh + (size_t)bh * TT * HD;
  const bf16_t* vbase = vt + (size_t)bh * TT * HD;

  // head-level constants
  float frm[2][4], w16c[4];
#pragma unroll
  for (int f = 0; f < 2; ++f)
#pragma unroll
    for (int r = 0; r < 4; ++r) frm[f][r] = (float)(16 * f + r) * mh2;
#pragma unroll
  for (int c = 0; c < 4; ++c) w16c[c] = fast_exp2((float)(16 * c) * mh2);

  // staging source offsets (per-lane), linear wave-uniform dests
  const int l8 = lane >> 3;
  const size_t kst = (size_t)(wid * 8 + l8) * 64 + ((lane & 7) ^ l8) * 8;
  const int vf_st = ((lane >> 2) & 3) ^ ((lane >> 4) & 3);
  const size_t vst = (size_t)(wid * 16 + (lane >> 2)) * 32 + ((lane & 3) ^ vf_st) * 8;

#define STAGE(BUF, KV0)                                                          \
  do {                                                                           \
    const bf16_t* ks_ = kbase + (size_t)(KV0) * HD + kst;                        \
    bf16_t* kd_ = &Klds[BUF][0][0] + wid * 512;                                  \
    gload16(ks_, kd_);                                                           \
    gload16(ks_ + 2048, kd_ + 2048);                                             \
    const bf16_t* vs_ = vbase + ((size_t)((KV0) >> 5)) * 2048 + vst;             \
    bf16_t* vd_ = &Vlds[BUF][0][0][0] + wid * 512;                               \
    gload16(vs_, vd_);                                                           \
    gload16(vs_ + 2048, vd_ + 2048);                                             \
  } while (0)

  bf16x8 qf[2][2];
#pragma unroll
  for (int f = 0; f < 2; ++f) {
    const bf16_t* qp = qbase + (size_t)(q0 + 16 * f + llo) * HD + 8 * lhi;
    qf[f][0] = *(const bf16x8*)qp;
    qf[f][1] = *(const bf16x8*)(qp + 32);
  }

  f32x4 acc[2][4] = {};
  float lsum[2][4] = {};
  const float bias0 = mh2 * (float)(llo - 4 * lhi - q0) - M0;

  const int kvT = jt * 128;                      // diagonal region base (block-uniform)
  int ksm = kvT - Dwin; ksm = (ksm < 0) ? 0 : (ksm & ~63);
  const int nTot = ((kvT - ksm) >> 6) + 2;       // covers [ksm, kvT+128); rows <= 2047

  STAGE(0, ksm);
  __syncthreads();

  const int krd0 = (lhi ^ (llo & 7)) * 16;       // K read slot bytes (h=0)
  const int krd1 = ((4 + lhi) ^ (llo & 7)) * 16; // h=1
  const int vrd = (lhi ^ ((llo & 3) ^ ((llo >> 2) & 3))) * 16;

  int buf = 0;
#pragma unroll 1
  for (int it = 0; it < nTot; ++it) {
    const int kv0 = ksm + (it << 6);
    if (it + 1 < nTot) STAGE(buf ^ 1, kv0 + 64);
    const char* kb = (const char*)&Klds[buf][0][0];
    const char* vb = (const char*)&Vlds[buf][0][0][0];
    f32x4 s[2][4];
#pragma unroll
    for (int c = 0; c < 4; ++c) {
      bf16x8 k0 = *(const bf16x8*)(kb + (16 * c + llo) * 128 + krd0);
      bf16x8 k1 = *(const bf16x8*)(kb + (16 * c + llo) * 128 + krd1);
      s[0][c] = MFMA_16x16x32_BF16(qf[0][0], k0, f32x4{});
      s[0][c] = MFMA_16x16x32_BF16(qf[0][1], k1, s[0][c]);
      s[1][c] = MFMA_16x16x32_BF16(qf[1][0], k0, f32x4{});
      s[1][c] = MFMA_16x16x32_BF16(qf[1][1], k1, s[1][c]);
    }
    bf16x8 vv[4][2];
#pragma unroll
    for (int d = 0; d < 4; ++d) {
      vv[d][0] = *(const bf16x8*)(vb + (16 * d + llo) * 64 + vrd);
      vv[d][1] = *(const bf16x8*)(vb + 4096 + (16 * d + llo) * 64 + vrd);
    }
    const float tb0 = fmaf(mh2, (float)kv0, bias0);
    const int dbase = q0 + 4 * lhi - llo - kv0;  // keep iff 16c-16f-r <= dbase
#pragma unroll
    for (int f = 0; f < 2; ++f) {
#pragma unroll
      for (int r = 0; r < 4; ++r) {
        const float rb = tb0 - frm[f][r];
#pragma unroll
        for (int c = 0; c < 4; ++c) {
          float pv = fast_exp2(fmaf(s[f][c][r], C1, rb)) * w16c[c];
          pv = (16 * c - 16 * f - r <= dbase) ? pv : 0.f;   // causal (no-op pre-diagonal)
          lsum[f][r] += pv;
          Plds[wid][16 * f + 4 * lhi + r][16 * c + llo] = (bf16_t)pv;
        }
      }
    }
#pragma unroll
    for (int f = 0; f < 2; ++f) {
      const bf16x8 pa0 = *(const bf16x8*)&Plds[wid][16 * f + llo][8 * lhi];
      const bf16x8 pa1 = *(const bf16x8*)&Plds[wid][16 * f + llo][32 + 8 * lhi];
#pragma unroll
      for (int d = 0; d < 4; ++d) {
        acc[f][d] = MFMA_16x16x32_BF16(pa0, vv[d][0], acc[f][d]);
        acc[f][d] = MFMA_16x16x32_BF16(pa1, vv[d][1], acc[f][d]);
      }
    }
    __syncthreads();   // reads of buf done + staging of buf^1 landed
    buf ^= 1;
  }
#undef STAGE

  // ---- one l-reduction across the 16-lane row group; epilogue ----
#pragma unroll
  for (int f = 0; f < 2; ++f) {
    float rl[4];
#pragma unroll
    for (int r = 0; r < 4; ++r) {
#pragma unroll
      for (int off = 1; off < 16; off <<= 1)
        lsum[f][r] += __shfl_xor(lsum[f][r], off, 64);
      rl[r] = __builtin_amdgcn_rcpf(lsum[f][r]);
    }
#pragma unroll
    for (int d = 0; d < 4; ++d)
#pragma unroll
      for (int r = 0; r < 4; ++r) {
        const int row = q0 + 16 * f + 4 * lhi + r;
        y[(size_t)(b * TT + row) * CC + h * HD + 16 * d + llo] =
            (bf16_t)(acc[f][d][r] * rl[r]);
      }
  }
}

// ---------------- launch ----------------
extern "C" void kernel_launch(void* const* d_in, const int* in_sizes, int n_in,
                              void* d_out, int out_size, void* d_ws, size_t ws_size,
                              hipStream_t stream) {
  const float* x       = (const float*)d_in[0];
  const float* Wq      = (const float*)d_in[1];
  const float* bq      = (const float*)d_in[2];
  const float* Wkv     = (const float*)d_in[3];
  const float* bkv     = (const float*)d_in[4];
  const float* Wp      = (const float*)d_in[5];
  const float* bp      = (const float*)d_in[6];
  const float* alibi_m = (const float*)d_in[7];
  float* out = (float*)d_out;

  char* w = (char*)d_ws;
  bf16_t* xb   = (bf16_t*)w; w += (size_t)MM * CC * 2;        // 16.78 MB (reused as yb)
  bf16_t* qkvh = (bf16_t*)w; w += SL * 3 * 2;                 // qkvh: q,k slices used
  bf16_t* btq  = (bf16_t*)w; w += (size_t)C3 * CC * 2;        //  6.29 MB
  bf16_t* wpt  = (bf16_t*)w; w += (size_t)CC * CC * 2;        //  2.10 MB
  bf16_t* vtb  = (bf16_t*)w; w += SL * 2;                     // 16.78 MB  [BH][T/32][64][32]
  float*  bcat = (float*)w;  w += (size_t)C3 * 4;             // 12 KB
  bf16_t* yb   = xb;  // xb dead after QKV GEMM -> alias

  dim3 tb(32, 8);
  cast_x_kernel<<<8192, 256, 0, stream>>>(x, xb, MM * CC / 4);
  transpose_cast_kernel<<<dim3(32, 32), tb, 0, stream>>>(Wq, btq, 1024, 1024);
  transpose_cast_kernel<<<dim3(64, 32), tb, 0, stream>>>(Wkv, btq + (size_t)1024 * 1024, 1024, 2048);
  transpose_cast_kernel<<<dim3(32, 32), tb, 0, stream>>>(Wp, wpt, 1024, 1024);
  concat_bias_kernel<<<12, 256, 0, stream>>>(bq, bkv, bcat);

  // QKV: 256x128 tiles, grid 768 (96/XCD, A band 2MB L2-resident);
  // V columns written directly into vtb (tiled V^T).
  gemm_kernel<1, bf16_t><<<dim3(768), 512, 0, stream>>>(
      xb, btq, qkvh, vtb, bcat, MM, C3, CC, 32);
  attn_kernel<<<dim3(1024), 256, 0, stream>>>(qkvh, qkvh + SL, vtb, alibi_m, yb);
  // proj: 256x128 tiles, grid 256
  gemm_kernel<0, float><<<dim3(256), 512, 0, stream>>>(
      yb, wpt, out, nullptr, bp, MM, CC, CC, 32);
}